// Round 20
// baseline (2314.724 us; speedup 1.0000x reference)
//
#include <hip/hip_runtime.h>
#include <hip/hip_fp16.h>
#include <math.h>

#define T_SEQ  512
#define BATCH  128
#define HID    256
#define NCLS   20
#define G4     1024   // 4*HID

typedef _Float16 v2h   __attribute__((ext_vector_type(2)));
typedef _Float16 f16x8 __attribute__((ext_vector_type(8)));
typedef float    f32x4 __attribute__((ext_vector_type(4)));
typedef float    f32x2 __attribute__((ext_vector_type(2)));

__device__ __forceinline__ float fdot2_acc(unsigned a, unsigned b, float acc) {
#if __has_builtin(__builtin_amdgcn_fdot2)
    return __builtin_amdgcn_fdot2(__builtin_bit_cast(v2h, a),
                                  __builtin_bit_cast(v2h, b), acc, false);
#else
    __half2 a2 = __builtin_bit_cast(__half2, a);
    __half2 b2 = __builtin_bit_cast(__half2, b);
    acc = fmaf(__low2float(a2),  __low2float(b2),  acc);
    acc = fmaf(__high2float(a2), __high2float(b2), acc);
    return acc;
#endif
}

// unpack 4 e4m3fn bytes (dword) -> two f16x2 words (k,k+1), (k+2,k+3). Exact.
__device__ __forceinline__ void unpack_e4m3x4(unsigned q, unsigned &lo, unsigned &hi) {
#if __has_builtin(__builtin_amdgcn_cvt_pk_f32_fp8)
    f32x2 a = __builtin_amdgcn_cvt_pk_f32_fp8((int)q, false);
    f32x2 b = __builtin_amdgcn_cvt_pk_f32_fp8((int)q, true);
    v2h l; l[0] = (_Float16)a[0]; l[1] = (_Float16)a[1];   // exact: e4m3 ⊂ f16
    v2h h; h[0] = (_Float16)b[0]; h[1] = (_Float16)b[1];
    lo = __builtin_bit_cast(unsigned, l);
    hi = __builtin_bit_cast(unsigned, h);
#else
    unsigned w0 = ((q & 0x00000080u) << 8) | ((q & 0x0000007Fu) << 7)
                | ((q & 0x00008000u) << 16) | ((q & 0x00007F00u) << 15);
    unsigned w1 = (((q >> 16) & 0x00000080u) << 8) | (((q >> 16) & 0x0000007Fu) << 7)
                | (((q >> 16) & 0x00008000u) << 16) | (((q >> 16) & 0x00007F00u) << 15);
    v2h s = {(_Float16)256.0f, (_Float16)256.0f};
    v2h l = __builtin_bit_cast(v2h, w0) * s;
    v2h h = __builtin_bit_cast(v2h, w1) * s;
    lo = __builtin_bit_cast(unsigned, l);
    hi = __builtin_bit_cast(unsigned, h);
#endif
}

// manual RNE f32 -> e4m3fn (pack kernel only)
__device__ unsigned pack_e4m3(float v) {
    unsigned s = (__float_as_uint(v) >> 24) & 0x80u;
    float av = fabsf(v);
    if (!(av < 448.0f)) return s | 0x7Eu;
    if (av < 0.015625f) {
        int q = (int)rintf(av * 512.0f);
        if (q <= 7) return s | (unsigned)q;
        return s | 0x08u;
    }
    int e; float man = frexpf(av, &e);
    int q = (int)rintf(man * 16.0f);
    int ebits = e - 1 + 7;
    if (q == 16) { q = 8; ebits += 1; }
    if (ebits > 15 || (ebits == 15 && q - 8 > 6)) return s | 0x7Eu;
    return s | ((unsigned)ebits << 3) | (unsigned)(q - 8);
}

// ---------------------------------------------------------------------------
// Pack U -> e4m3 quads over k: u8[dir][kq][col].
// ---------------------------------------------------------------------------
__global__ __launch_bounds__(256) void pack_u8_v20(
    const float* __restrict__ U_f, const float* __restrict__ U_b,
    unsigned* __restrict__ u8out)
{
    int idx = blockIdx.x * 256 + threadIdx.x;
    if (idx >= 2 * 64 * 1024) return;
    int dir = idx >> 16;
    int rem = idx & 65535;
    int kq  = rem >> 10;
    int col = rem & 1023;
    const float* __restrict__ U = dir ? U_b : U_f;
    unsigned b0 = pack_e4m3(U[(size_t)(4 * kq + 0) * G4 + col]);
    unsigned b1 = pack_e4m3(U[(size_t)(4 * kq + 1) * G4 + col]);
    unsigned b2 = pack_e4m3(U[(size_t)(4 * kq + 2) * G4 + col]);
    unsigned b3 = pack_e4m3(U[(size_t)(4 * kq + 3) * G4 + col]);
    u8out[idx] = b0 | (b1 << 8) | (b2 << 16) | (b3 << 24);
}

// ---------------------------------------------------------------------------
// Kernel A: input projection via f16 MFMA 16x16x32 (v18, proven).
// ---------------------------------------------------------------------------
__global__ __launch_bounds__(256) void xw_gemm_mfma_v20(
    const int*   __restrict__ tokens,
    const float* __restrict__ emb_table,
    const float* __restrict__ W_f, const float* __restrict__ b_f,
    const float* __restrict__ W_b, const float* __restrict__ b_b,
    float* __restrict__ xw, int chunk0, int chunk_len)
{
    const int dir = blockIdx.z;
    const float* __restrict__ W    = dir ? W_b : W_f;
    const float* __restrict__ bias = dir ? b_b : b_f;
    const int mtile = blockIdx.x;
    const int ntile = blockIdx.y;
    const int tid = threadIdx.x;

    __shared__ _Float16 Ah[32][264];
    __shared__ _Float16 Wt[256][40];
    __shared__ int tok[32];

    if (tid < 32) {
        int m = mtile * 32 + tid;
        int s_local = m >> 7;
        int b = m & 127;
        int tt = chunk0 + s_local;
        if (dir) tt = T_SEQ - 1 - tt;
        int token = tokens[b * T_SEQ + tt];
        tok[tid] = token < 0 ? 0 : (token > 49999 ? 49999 : token);
    }
    __syncthreads();

    {
        int r = tid >> 3, c8 = tid & 7;
        const float4* src = (const float4*)(emb_table + (size_t)tok[r] * 256);
        #pragma unroll
        for (int i = 0; i < 8; ++i) {
            int c4 = c8 + i * 8;
            float4 v = src[c4];
            int k0 = c4 * 4;
            Ah[r][k0 + 0] = (_Float16)v.x;
            Ah[r][k0 + 1] = (_Float16)v.y;
            Ah[r][k0 + 2] = (_Float16)v.z;
            Ah[r][k0 + 3] = (_Float16)v.w;
        }
    }

    const int wv   = tid >> 6;
    const int lane = tid & 63;
    const int lr   = lane & 15;
    const int koff = (lane >> 4) * 8;
    const int n0   = wv * 64;

    f32x4 acc0[4], acc1[4];
    #pragma unroll
    for (int nf = 0; nf < 4; ++nf) {
        float bv = bias[ntile * 256 + n0 + nf * 16 + lr];
        acc0[nf] = (f32x4){bv, bv, bv, bv};
        acc1[nf] = (f32x4){bv, bv, bv, bv};
    }

    for (int kc = 0; kc < 8; ++kc) {
        __syncthreads();
        #pragma unroll
        for (int i = 0; i < 32; ++i) {
            int idx = tid + i * 256;
            int k = idx >> 8, n = idx & 255;
            Wt[n][k] = (_Float16)W[(size_t)(kc * 32 + k) * G4 + ntile * 256 + n];
        }
        __syncthreads();

        f16x8 a0 = *(const f16x8*)&Ah[lr][kc * 32 + koff];
        f16x8 a1 = *(const f16x8*)&Ah[16 + lr][kc * 32 + koff];
        #pragma unroll
        for (int nf = 0; nf < 4; ++nf) {
            f16x8 bf = *(const f16x8*)&Wt[n0 + nf * 16 + lr][koff];
            acc0[nf] = __builtin_amdgcn_mfma_f32_16x16x32_f16(a0, bf, acc0[nf], 0, 0, 0);
            acc1[nf] = __builtin_amdgcn_mfma_f32_16x16x32_f16(a1, bf, acc1[nf], 0, 0, 0);
        }
    }

    const int rbase = (lane >> 4) * 4;
    #pragma unroll
    for (int m = 0; m < 2; ++m) {
        #pragma unroll
        for (int nf = 0; nf < 4; ++nf) {
            f32x4 av = m ? acc1[nf] : acc0[nf];
            #pragma unroll
            for (int i = 0; i < 4; ++i) {
                int mrow = mtile * 32 + m * 16 + rbase + i;
                int s_local = mrow >> 7, b = mrow & 127;
                int col = ntile * 256 + n0 + nf * 16 + lr;
                xw[(((size_t)dir * chunk_len + s_local) * BATCH + b) * G4 + col] = av[i];
            }
        }
    }
}

// ---------------------------------------------------------------------------
// Kernel B: persistent scan, ONE (row,dir) per block -> 256 blocks (all CUs).
// 1024 threads = 1024 gate-cols. fp8 U (0.25 MB/block/step). xw for step
// sl+1 prefetched during step sl (hides HBM latency across barriers).
// Phase 2: threads 0..127 own unit-pairs; c in regs.
// ---------------------------------------------------------------------------
__global__ __launch_bounds__(1024) void lstm_scan_v20(
    const float* __restrict__ xw,          // [2][chunk][128][1024]
    const unsigned* __restrict__ u8,       // [2][64][1024]
    float* __restrict__ h_state,           // [2][128][256]
    float* __restrict__ c_state,           // [2][128][256]
    int chunk_len)
{
    const int row = blockIdx.x;            // batch row 0..127
    const int dir = blockIdx.y;
    const int tid = threadIdx.x;
    const unsigned* __restrict__ U8 = u8 + (size_t)dir * 65536;

    __shared__ unsigned hs16[128];         // h packed f16x2 over k
    __shared__ float    zs[1024];

    const int up = tid & 127;              // phase-2: unit pair (threads 0..127)
    float c0r = 0.0f, c1r = 0.0f, h0r = 0.0f, h1r = 0.0f;
    if (tid < 128) {
        size_t base = ((size_t)dir * BATCH + row) * HID + 2 * up;
        c0r = c_state[base];
        c1r = c_state[base + 1];
        h0r = h_state[base];
        h1r = h_state[base + 1];
        __half2 hh = __floats2half2_rn(h0r, h1r);
        hs16[up] = *(unsigned*)&hh;
    }
    __syncthreads();

    const float* xwbase = xw + ((size_t)dir * chunk_len * BATCH + row) * G4;
    float xw_next = xwbase[tid];           // step 0

    for (int sl = 0; sl < chunk_len; ++sl) {
        float acc = xw_next;
        if (sl + 1 < chunk_len)            // prefetch next step's xw early
            xw_next = xwbase[(size_t)(sl + 1) * BATCH * G4 + tid];

        unsigned ub[8], un[8];
        #pragma unroll
        for (int j = 0; j < 8; ++j) ub[j] = U8[(size_t)j * G4 + tid];
        #pragma unroll
        for (int blk = 0; blk < 8; ++blk) {
            int nb = (blk + 1) & 7;        // wrap primes blk0 for next step
            #pragma unroll
            for (int j = 0; j < 8; ++j)
                un[j] = U8[(size_t)(nb * 8 + j) * G4 + tid];
            #pragma unroll
            for (int j = 0; j < 8; ++j) {
                int kq = blk * 8 + j;
                unsigned ulo, uhi;
                unpack_e4m3x4(ub[j], ulo, uhi);
                acc = fdot2_acc(hs16[2 * kq],     ulo, acc);
                acc = fdot2_acc(hs16[2 * kq + 1], uhi, acc);
            }
            #pragma unroll
            for (int j = 0; j < 8; ++j) ub[j] = un[j];
        }
        zs[tid] = acc;
        __syncthreads();

        if (tid < 128) {
            float zi0 = zs[2 * up],       zi1 = zs[2 * up + 1];
            float zf0 = zs[256 + 2 * up], zf1 = zs[256 + 2 * up + 1];
            float zg0 = zs[512 + 2 * up], zg1 = zs[512 + 2 * up + 1];
            float zo0 = zs[768 + 2 * up], zo1 = zs[768 + 2 * up + 1];
            float si0 = 1.0f / (1.0f + expf(-zi0)), si1 = 1.0f / (1.0f + expf(-zi1));
            float sf0 = 1.0f / (1.0f + expf(-zf0)), sf1 = 1.0f / (1.0f + expf(-zf1));
            float tg0 = tanhf(zg0),                 tg1 = tanhf(zg1);
            float so0 = 1.0f / (1.0f + expf(-zo0)), so1 = 1.0f / (1.0f + expf(-zo1));
            c0r = fmaf(sf0, c0r, si0 * tg0);
            c1r = fmaf(sf1, c1r, si1 * tg1);
            h0r = so0 * tanhf(c0r);
            h1r = so1 * tanhf(c1r);
            __half2 hh = __floats2half2_rn(h0r, h1r);
            hs16[up] = *(unsigned*)&hh;
        }
        __syncthreads();
    }

    if (tid < 128) {
        size_t base = ((size_t)dir * BATCH + row) * HID + 2 * up;
        h_state[base]     = h0r;
        h_state[base + 1] = h1r;
        c_state[base]     = c0r;
        c_state[base + 1] = c1r;
    }
}

// ---------------------------------------------------------------------------
// Fallback per-step kernel (tiny workspace).
// ---------------------------------------------------------------------------
__global__ __launch_bounds__(256) void lstm_step_fb(
    const int*   __restrict__ tokens,
    const float* __restrict__ emb_table,
    const float* __restrict__ W_f, const float* __restrict__ U_f, const float* __restrict__ b_f,
    const float* __restrict__ W_b, const float* __restrict__ U_b, const float* __restrict__ b_b,
    const float* __restrict__ h_in, float* __restrict__ h_out,
    float* __restrict__ c_state, int step)
{
    const int rt  = blockIdx.x;
    const int ut  = blockIdx.y;
    const int dir = blockIdx.z;
    const int tid = threadIdx.x;
    const float* __restrict__ W  = dir ? W_b : W_f;
    const float* __restrict__ U  = dir ? U_b : U_f;
    const float* __restrict__ bs = dir ? b_b : b_f;

    __shared__ int   tok[8];
    __shared__ float xs[8][260];
    __shared__ float hs[8][260];
    __shared__ float zsf[4][8][32];

    const int tt = dir ? (T_SEQ - 1 - step) : step;
    if (tid < 8) {
        int token = tokens[(rt * 8 + tid) * T_SEQ + tt];
        tok[tid] = (token < 0) ? 0 : (token > 49999 ? 49999 : token);
    }
    __syncthreads();
    for (int i = tid; i < 2048; i += 256) {
        int r = i >> 8, k = i & 255;
        xs[r][k] = emb_table[(size_t)tok[r] * 256 + k];
        hs[r][k] = h_in[((size_t)dir * BATCH + rt * 8 + r) * HID + k];
    }
    __syncthreads();

    const int g = tid >> 6, r = (tid >> 3) & 7, q = tid & 7;
    const int col = g * 256 + ut * 32 + q * 4;
    const float4* __restrict__ W4 = (const float4*)(W + col);
    const float4* __restrict__ U4 = (const float4*)(U + col);
    float4 acc = *(const float4*)(bs + col);
    #pragma unroll 4
    for (int k = 0; k < 256; ++k) {
        float xv = xs[r][k], hv = hs[r][k];
        float4 w = W4[(size_t)k * 256];
        float4 u = U4[(size_t)k * 256];
        acc.x = fmaf(xv, w.x, acc.x); acc.y = fmaf(xv, w.y, acc.y);
        acc.z = fmaf(xv, w.z, acc.z); acc.w = fmaf(xv, w.w, acc.w);
        acc.x = fmaf(hv, u.x, acc.x); acc.y = fmaf(hv, u.y, acc.y);
        acc.z = fmaf(hv, u.z, acc.z); acc.w = fmaf(hv, u.w, acc.w);
    }
    *(float4*)&zsf[g][r][q * 4] = acc;
    __syncthreads();
    {
        const int r2 = tid >> 5, j2 = tid & 31;
        float si = 1.0f / (1.0f + expf(-zsf[0][r2][j2]));
        float sf = 1.0f / (1.0f + expf(-zsf[1][r2][j2]));
        float tg = tanhf(zsf[2][r2][j2]);
        float so = 1.0f / (1.0f + expf(-zsf[3][r2][j2]));
        size_t idx = ((size_t)dir * BATCH + rt * 8 + r2) * HID + ut * 32 + j2;
        float cv = fmaf(sf, c_state[idx], si * tg);
        c_state[idx] = cv;
        h_out[idx] = so * tanhf(cv);
    }
}

// ---------------------------------------------------------------------------
// Dense + softmax (f32): one block per batch row.
// ---------------------------------------------------------------------------
__global__ __launch_bounds__(64) void dense_softmax_v20(
    const float* __restrict__ h_final,
    const float* __restrict__ W_d, const float* __restrict__ b_d,
    float* __restrict__ out)
{
    const int rrow = blockIdx.x;
    const int cth  = threadIdx.x;
    __shared__ float lg[NCLS];
    if (cth < NCLS) {
        const float* hf = h_final + (size_t)rrow * HID;
        const float* hb = h_final + ((size_t)BATCH + rrow) * HID;
        float s = b_d[cth];
        for (int k = 0; k < HID; ++k) s = fmaf(hf[k], W_d[k * NCLS + cth], s);
        for (int k = 0; k < HID; ++k) s = fmaf(hb[k], W_d[(HID + k) * NCLS + cth], s);
        lg[cth] = s;
    }
    __syncthreads();
    if (cth == 0) {
        float m = lg[0];
        for (int c = 1; c < NCLS; ++c) m = fmaxf(m, lg[c]);
        float e[NCLS]; float ssum = 0.0f;
        for (int c = 0; c < NCLS; ++c) { e[c] = expf(lg[c] - m); ssum += e[c]; }
        float inv = 1.0f / ssum;
        for (int c = 0; c < NCLS; ++c) out[rrow * NCLS + c] = e[c] * inv;
    }
}

extern "C" void kernel_launch(void* const* d_in, const int* in_sizes, int n_in,
                              void* d_out, int out_size, void* d_ws, size_t ws_size,
                              hipStream_t stream)
{
    const int*   tokens = (const int*)d_in[0];
    const float* emb    = (const float*)d_in[1];
    const float* W_f    = (const float*)d_in[2];
    const float* U_f    = (const float*)d_in[3];
    const float* b_f    = (const float*)d_in[4];
    const float* W_b    = (const float*)d_in[5];
    const float* U_b    = (const float*)d_in[6];
    const float* b_b    = (const float*)d_in[7];
    const float* W_d    = (const float*)d_in[8];
    const float* b_d    = (const float*)d_in[9];
    float* out = (float*)d_out;
    float* ws  = (float*)d_ws;

    const size_t HSLOT = (size_t)2 * BATCH * HID;        // 65536 floats
    const size_t U8SZ  = (size_t)2 * 64 * G4;            // 131072 dwords
    int chunk = 0;
    const int cand[4] = {512, 128, 64, 16};
    for (int i = 0; i < 4; ++i) {
        size_t need = ((size_t)2 * cand[i] * BATCH * G4 + 2 * HSLOT + U8SZ) * sizeof(float);
        if (ws_size >= need) { chunk = cand[i]; break; }
    }

    if (chunk == 0) {
        float* hbuf0 = ws;
        float* cbuf  = hbuf0 + HSLOT;
        float* hbuf1 = cbuf + HSLOT;
        hipMemsetAsync(hbuf0, 0, 2 * HSLOT * sizeof(float), stream);
        float* hin = hbuf0; float* hout = hbuf1;
        for (int s = 0; s < T_SEQ; ++s) {
            lstm_step_fb<<<dim3(16, 8, 2), 256, 0, stream>>>(
                tokens, emb, W_f, U_f, b_f, W_b, U_b, b_b, hin, hout, cbuf, s);
            float* tmp = hin; hin = hout; hout = tmp;
        }
        dense_softmax_v20<<<dim3(BATCH), 64, 0, stream>>>(hin, W_d, b_d, out);
        return;
    }

    float*    xw     = ws;                                  // [2][chunk][128][1024]
    float*    hstate = xw + (size_t)2 * chunk * BATCH * G4; // [2][128][256]
    float*    cstate = hstate + HSLOT;                      // [2][128][256]
    unsigned* u8     = (unsigned*)(cstate + HSLOT);         // [2][64][1024]

    hipMemsetAsync(hstate, 0, 2 * HSLOT * sizeof(float), stream);  // h0 + c0

    pack_u8_v20<<<dim3(512), 256, 0, stream>>>(U_f, U_b, u8);

    for (int c0 = 0; c0 < T_SEQ; c0 += chunk) {
        xw_gemm_mfma_v20<<<dim3(chunk * BATCH / 32, 4, 2), 256, 0, stream>>>(
            tokens, emb, W_f, b_f, W_b, b_b, xw, c0, chunk);
        lstm_scan_v20<<<dim3(128, 2), 1024, 0, stream>>>(
            xw, u8, hstate, cstate, chunk);
    }
    dense_softmax_v20<<<dim3(BATCH), 64, 0, stream>>>(hstate, W_d, b_d, out);
}

// Round 21
// 1788.706 us; speedup vs baseline: 1.2941x; 1.2941x over previous
//
#include <hip/hip_runtime.h>
#include <hip/hip_fp16.h>
#include <math.h>

#define T_SEQ  512
#define BATCH  128
#define HID    256
#define NCLS   20
#define G4     1024   // 4*HID

typedef _Float16 v2h   __attribute__((ext_vector_type(2)));
typedef _Float16 f16x8 __attribute__((ext_vector_type(8)));
typedef float    f32x4 __attribute__((ext_vector_type(4)));
typedef float    f32x2 __attribute__((ext_vector_type(2)));

__device__ __forceinline__ float fdot2_acc(unsigned a, unsigned b, float acc) {
#if __has_builtin(__builtin_amdgcn_fdot2)
    return __builtin_amdgcn_fdot2(__builtin_bit_cast(v2h, a),
                                  __builtin_bit_cast(v2h, b), acc, false);
#else
    __half2 a2 = __builtin_bit_cast(__half2, a);
    __half2 b2 = __builtin_bit_cast(__half2, b);
    acc = fmaf(__low2float(a2),  __low2float(b2),  acc);
    acc = fmaf(__high2float(a2), __high2float(b2), acc);
    return acc;
#endif
}

// fast gate nonlinearities (hw v_exp_f32; ~1e-6 rel err, washes out in the
// 512-wide dense reduction; absmax headroom is 4x)
__device__ __forceinline__ float fsig(float x)  { return 1.0f / (1.0f + __expf(-x)); }
__device__ __forceinline__ float ftanh(float x) { return 1.0f - 2.0f / (__expf(2.0f * x) + 1.0f); }

// unpack 4 e4m3fn bytes (dword) -> two f16x2 words. Exact (e4m3 ⊂ f16).
__device__ __forceinline__ void unpack_e4m3x4(unsigned q, unsigned &lo, unsigned &hi) {
#if __has_builtin(__builtin_amdgcn_cvt_pk_f32_fp8)
    f32x2 a = __builtin_amdgcn_cvt_pk_f32_fp8((int)q, false);
    f32x2 b = __builtin_amdgcn_cvt_pk_f32_fp8((int)q, true);
    v2h l; l[0] = (_Float16)a[0]; l[1] = (_Float16)a[1];
    v2h h; h[0] = (_Float16)b[0]; h[1] = (_Float16)b[1];
    lo = __builtin_bit_cast(unsigned, l);
    hi = __builtin_bit_cast(unsigned, h);
#else
    unsigned w0 = ((q & 0x00000080u) << 8) | ((q & 0x0000007Fu) << 7)
                | ((q & 0x00008000u) << 16) | ((q & 0x00007F00u) << 15);
    unsigned w1 = (((q >> 16) & 0x00000080u) << 8) | (((q >> 16) & 0x0000007Fu) << 7)
                | (((q >> 16) & 0x00008000u) << 16) | (((q >> 16) & 0x00007F00u) << 15);
    v2h s = {(_Float16)256.0f, (_Float16)256.0f};
    v2h l = __builtin_bit_cast(v2h, w0) * s;
    v2h h = __builtin_bit_cast(v2h, w1) * s;
    lo = __builtin_bit_cast(unsigned, l);
    hi = __builtin_bit_cast(unsigned, h);
#endif
}

// manual RNE f32 -> e4m3fn (pack kernel only)
__device__ unsigned pack_e4m3(float v) {
    unsigned s = (__float_as_uint(v) >> 24) & 0x80u;
    float av = fabsf(v);
    if (!(av < 448.0f)) return s | 0x7Eu;
    if (av < 0.015625f) {
        int q = (int)rintf(av * 512.0f);
        if (q <= 7) return s | (unsigned)q;
        return s | 0x08u;
    }
    int e; float man = frexpf(av, &e);
    int q = (int)rintf(man * 16.0f);
    int ebits = e - 1 + 7;
    if (q == 16) { q = 8; ebits += 1; }
    if (ebits > 15 || (ebits == 15 && q - 8 > 6)) return s | 0x7Eu;
    return s | ((unsigned)ebits << 3) | (unsigned)(q - 8);
}

// ---------------------------------------------------------------------------
// Pack U -> e4m3 quads over k: u8[dir][kq][col].
// ---------------------------------------------------------------------------
__global__ __launch_bounds__(256) void pack_u8_v21(
    const float* __restrict__ U_f, const float* __restrict__ U_b,
    unsigned* __restrict__ u8out)
{
    int idx = blockIdx.x * 256 + threadIdx.x;
    if (idx >= 2 * 64 * 1024) return;
    int dir = idx >> 16;
    int rem = idx & 65535;
    int kq  = rem >> 10;
    int col = rem & 1023;
    const float* __restrict__ U = dir ? U_b : U_f;
    unsigned b0 = pack_e4m3(U[(size_t)(4 * kq + 0) * G4 + col]);
    unsigned b1 = pack_e4m3(U[(size_t)(4 * kq + 1) * G4 + col]);
    unsigned b2 = pack_e4m3(U[(size_t)(4 * kq + 2) * G4 + col]);
    unsigned b3 = pack_e4m3(U[(size_t)(4 * kq + 3) * G4 + col]);
    u8out[idx] = b0 | (b1 << 8) | (b2 << 16) | (b3 << 24);
}

// ---------------------------------------------------------------------------
// Kernel A: input projection via f16 MFMA 16x16x32 (v18, proven).
// ---------------------------------------------------------------------------
__global__ __launch_bounds__(256) void xw_gemm_mfma_v21(
    const int*   __restrict__ tokens,
    const float* __restrict__ emb_table,
    const float* __restrict__ W_f, const float* __restrict__ b_f,
    const float* __restrict__ W_b, const float* __restrict__ b_b,
    float* __restrict__ xw, int chunk0, int chunk_len)
{
    const int dir = blockIdx.z;
    const float* __restrict__ W    = dir ? W_b : W_f;
    const float* __restrict__ bias = dir ? b_b : b_f;
    const int mtile = blockIdx.x;
    const int ntile = blockIdx.y;
    const int tid = threadIdx.x;

    __shared__ _Float16 Ah[32][264];
    __shared__ _Float16 Wt[256][40];
    __shared__ int tok[32];

    if (tid < 32) {
        int m = mtile * 32 + tid;
        int s_local = m >> 7;
        int b = m & 127;
        int tt = chunk0 + s_local;
        if (dir) tt = T_SEQ - 1 - tt;
        int token = tokens[b * T_SEQ + tt];
        tok[tid] = token < 0 ? 0 : (token > 49999 ? 49999 : token);
    }
    __syncthreads();

    {
        int r = tid >> 3, c8 = tid & 7;
        const float4* src = (const float4*)(emb_table + (size_t)tok[r] * 256);
        #pragma unroll
        for (int i = 0; i < 8; ++i) {
            int c4 = c8 + i * 8;
            float4 v = src[c4];
            int k0 = c4 * 4;
            Ah[r][k0 + 0] = (_Float16)v.x;
            Ah[r][k0 + 1] = (_Float16)v.y;
            Ah[r][k0 + 2] = (_Float16)v.z;
            Ah[r][k0 + 3] = (_Float16)v.w;
        }
    }

    const int wv   = tid >> 6;
    const int lane = tid & 63;
    const int lr   = lane & 15;
    const int koff = (lane >> 4) * 8;
    const int n0   = wv * 64;

    f32x4 acc0[4], acc1[4];
    #pragma unroll
    for (int nf = 0; nf < 4; ++nf) {
        float bv = bias[ntile * 256 + n0 + nf * 16 + lr];
        acc0[nf] = (f32x4){bv, bv, bv, bv};
        acc1[nf] = (f32x4){bv, bv, bv, bv};
    }

    for (int kc = 0; kc < 8; ++kc) {
        __syncthreads();
        #pragma unroll
        for (int i = 0; i < 32; ++i) {
            int idx = tid + i * 256;
            int k = idx >> 8, n = idx & 255;
            Wt[n][k] = (_Float16)W[(size_t)(kc * 32 + k) * G4 + ntile * 256 + n];
        }
        __syncthreads();

        f16x8 a0 = *(const f16x8*)&Ah[lr][kc * 32 + koff];
        f16x8 a1 = *(const f16x8*)&Ah[16 + lr][kc * 32 + koff];
        #pragma unroll
        for (int nf = 0; nf < 4; ++nf) {
            f16x8 bf = *(const f16x8*)&Wt[n0 + nf * 16 + lr][koff];
            acc0[nf] = __builtin_amdgcn_mfma_f32_16x16x32_f16(a0, bf, acc0[nf], 0, 0, 0);
            acc1[nf] = __builtin_amdgcn_mfma_f32_16x16x32_f16(a1, bf, acc1[nf], 0, 0, 0);
        }
    }

    const int rbase = (lane >> 4) * 4;
    #pragma unroll
    for (int m = 0; m < 2; ++m) {
        #pragma unroll
        for (int nf = 0; nf < 4; ++nf) {
            f32x4 av = m ? acc1[nf] : acc0[nf];
            #pragma unroll
            for (int i = 0; i < 4; ++i) {
                int mrow = mtile * 32 + m * 16 + rbase + i;
                int s_local = mrow >> 7, b = mrow & 127;
                int col = ntile * 256 + n0 + nf * 16 + lr;
                xw[(((size_t)dir * chunk_len + s_local) * BATCH + b) * G4 + col] = av[i];
            }
        }
    }
}

// ---------------------------------------------------------------------------
// Kernel B: persistent scan, 1 (row,dir)/block, 256 blocks, 1024 threads.
// v21 changes vs v20: (1) gate nonlinearities applied IN PHASE 1 by all 1024
// threads (zs holds activated values); (2) fast __expf-based sigmoid/tanh;
// (3) 2-block-deep U prefetch (16 loads in flight vs ~250cy L2 latency).
// Phase 2 (128 threads): c=fmaf + 1 tanh per unit only.
// ---------------------------------------------------------------------------
__global__ __launch_bounds__(1024) void lstm_scan_v21(
    const float* __restrict__ xw,          // [2][chunk][128][1024]
    const unsigned* __restrict__ u8,       // [2][64][1024]
    float* __restrict__ h_state,           // [2][128][256]
    float* __restrict__ c_state,           // [2][128][256]
    int chunk_len)
{
    const int row = blockIdx.x;
    const int dir = blockIdx.y;
    const int tid = threadIdx.x;
    const int gate = tid >> 8;             // 0..3 (wave-uniform)
    const unsigned* __restrict__ U8 = u8 + (size_t)dir * 65536;

    __shared__ unsigned hs16[128];
    __shared__ float    zs[1024];          // ACTIVATED gate values

    const int up = tid & 127;
    float c0r = 0.0f, c1r = 0.0f, h0r = 0.0f, h1r = 0.0f;
    if (tid < 128) {
        size_t base = ((size_t)dir * BATCH + row) * HID + 2 * up;
        c0r = c_state[base];
        c1r = c_state[base + 1];
        h0r = h_state[base];
        h1r = h_state[base + 1];
        __half2 hh = __floats2half2_rn(h0r, h1r);
        hs16[up] = *(unsigned*)&hh;
    }
    __syncthreads();

    const float* xwbase = xw + ((size_t)dir * chunk_len * BATCH + row) * G4;
    float xw_next = xwbase[tid];

    for (int sl = 0; sl < chunk_len; ++sl) {
        float acc = xw_next;
        if (sl + 1 < chunk_len)
            xw_next = xwbase[(size_t)(sl + 1) * BATCH * G4 + tid];

        // 2-block-deep rolling prefetch of U (16 dwords in flight)
        unsigned u0[8], u1[8], u2[8];
        #pragma unroll
        for (int j = 0; j < 8; ++j) u0[j] = U8[(size_t)j * G4 + tid];
        #pragma unroll
        for (int j = 0; j < 8; ++j) u1[j] = U8[(size_t)(8 + j) * G4 + tid];
        #pragma unroll
        for (int blk = 0; blk < 8; ++blk) {
            int nb = (blk + 2) & 7;        // wrap primes next step (L1-hot)
            #pragma unroll
            for (int j = 0; j < 8; ++j)
                u2[j] = U8[(size_t)(nb * 8 + j) * G4 + tid];
            #pragma unroll
            for (int j = 0; j < 8; ++j) {
                int kq = blk * 8 + j;
                unsigned ulo, uhi;
                unpack_e4m3x4(u0[j], ulo, uhi);
                acc = fdot2_acc(hs16[2 * kq],     ulo, acc);
                acc = fdot2_acc(hs16[2 * kq + 1], uhi, acc);
            }
            #pragma unroll
            for (int j = 0; j < 8; ++j) { u0[j] = u1[j]; u1[j] = u2[j]; }
        }
        // apply gate nonlinearity HERE (all 1024 threads active)
        zs[tid] = (gate == 2) ? ftanh(acc) : fsig(acc);
        __syncthreads();

        if (tid < 128) {
            float si0 = zs[2 * up],       si1 = zs[2 * up + 1];
            float sf0 = zs[256 + 2 * up], sf1 = zs[256 + 2 * up + 1];
            float tg0 = zs[512 + 2 * up], tg1 = zs[512 + 2 * up + 1];
            float so0 = zs[768 + 2 * up], so1 = zs[768 + 2 * up + 1];
            c0r = fmaf(sf0, c0r, si0 * tg0);
            c1r = fmaf(sf1, c1r, si1 * tg1);
            h0r = so0 * ftanh(c0r);
            h1r = so1 * ftanh(c1r);
            __half2 hh = __floats2half2_rn(h0r, h1r);
            hs16[up] = *(unsigned*)&hh;
        }
        __syncthreads();
    }

    if (tid < 128) {
        size_t base = ((size_t)dir * BATCH + row) * HID + 2 * up;
        h_state[base]     = h0r;
        h_state[base + 1] = h1r;
        c_state[base]     = c0r;
        c_state[base + 1] = c1r;
    }
}

// ---------------------------------------------------------------------------
// Fallback per-step kernel (tiny workspace).
// ---------------------------------------------------------------------------
__global__ __launch_bounds__(256) void lstm_step_fb(
    const int*   __restrict__ tokens,
    const float* __restrict__ emb_table,
    const float* __restrict__ W_f, const float* __restrict__ U_f, const float* __restrict__ b_f,
    const float* __restrict__ W_b, const float* __restrict__ U_b, const float* __restrict__ b_b,
    const float* __restrict__ h_in, float* __restrict__ h_out,
    float* __restrict__ c_state, int step)
{
    const int rt  = blockIdx.x;
    const int ut  = blockIdx.y;
    const int dir = blockIdx.z;
    const int tid = threadIdx.x;
    const float* __restrict__ W  = dir ? W_b : W_f;
    const float* __restrict__ U  = dir ? U_b : U_f;
    const float* __restrict__ bs = dir ? b_b : b_f;

    __shared__ int   tok[8];
    __shared__ float xs[8][260];
    __shared__ float hs[8][260];
    __shared__ float zsf[4][8][32];

    const int tt = dir ? (T_SEQ - 1 - step) : step;
    if (tid < 8) {
        int token = tokens[(rt * 8 + tid) * T_SEQ + tt];
        tok[tid] = (token < 0) ? 0 : (token > 49999 ? 49999 : token);
    }
    __syncthreads();
    for (int i = tid; i < 2048; i += 256) {
        int r = i >> 8, k = i & 255;
        xs[r][k] = emb_table[(size_t)tok[r] * 256 + k];
        hs[r][k] = h_in[((size_t)dir * BATCH + rt * 8 + r) * HID + k];
    }
    __syncthreads();

    const int g = tid >> 6, r = (tid >> 3) & 7, q = tid & 7;
    const int col = g * 256 + ut * 32 + q * 4;
    const float4* __restrict__ W4 = (const float4*)(W + col);
    const float4* __restrict__ U4 = (const float4*)(U + col);
    float4 acc = *(const float4*)(bs + col);
    #pragma unroll 4
    for (int k = 0; k < 256; ++k) {
        float xv = xs[r][k], hv = hs[r][k];
        float4 w = W4[(size_t)k * 256];
        float4 u = U4[(size_t)k * 256];
        acc.x = fmaf(xv, w.x, acc.x); acc.y = fmaf(xv, w.y, acc.y);
        acc.z = fmaf(xv, w.z, acc.z); acc.w = fmaf(xv, w.w, acc.w);
        acc.x = fmaf(hv, u.x, acc.x); acc.y = fmaf(hv, u.y, acc.y);
        acc.z = fmaf(hv, u.z, acc.z); acc.w = fmaf(hv, u.w, acc.w);
    }
    *(float4*)&zsf[g][r][q * 4] = acc;
    __syncthreads();
    {
        const int r2 = tid >> 5, j2 = tid & 31;
        float si = 1.0f / (1.0f + expf(-zsf[0][r2][j2]));
        float sf = 1.0f / (1.0f + expf(-zsf[1][r2][j2]));
        float tg = tanhf(zsf[2][r2][j2]);
        float so = 1.0f / (1.0f + expf(-zsf[3][r2][j2]));
        size_t idx = ((size_t)dir * BATCH + rt * 8 + r2) * HID + ut * 32 + j2;
        float cv = fmaf(sf, c_state[idx], si * tg);
        c_state[idx] = cv;
        h_out[idx] = so * tanhf(cv);
    }
}

// ---------------------------------------------------------------------------
// Dense + softmax (f32): one block per batch row.
// ---------------------------------------------------------------------------
__global__ __launch_bounds__(64) void dense_softmax_v21(
    const float* __restrict__ h_final,
    const float* __restrict__ W_d, const float* __restrict__ b_d,
    float* __restrict__ out)
{
    const int rrow = blockIdx.x;
    const int cth  = threadIdx.x;
    __shared__ float lg[NCLS];
    if (cth < NCLS) {
        const float* hf = h_final + (size_t)rrow * HID;
        const float* hb = h_final + ((size_t)BATCH + rrow) * HID;
        float s = b_d[cth];
        for (int k = 0; k < HID; ++k) s = fmaf(hf[k], W_d[k * NCLS + cth], s);
        for (int k = 0; k < HID; ++k) s = fmaf(hb[k], W_d[(HID + k) * NCLS + cth], s);
        lg[cth] = s;
    }
    __syncthreads();
    if (cth == 0) {
        float m = lg[0];
        for (int c = 1; c < NCLS; ++c) m = fmaxf(m, lg[c]);
        float e[NCLS]; float ssum = 0.0f;
        for (int c = 0; c < NCLS; ++c) { e[c] = expf(lg[c] - m); ssum += e[c]; }
        float inv = 1.0f / ssum;
        for (int c = 0; c < NCLS; ++c) out[rrow * NCLS + c] = e[c] * inv;
    }
}

extern "C" void kernel_launch(void* const* d_in, const int* in_sizes, int n_in,
                              void* d_out, int out_size, void* d_ws, size_t ws_size,
                              hipStream_t stream)
{
    const int*   tokens = (const int*)d_in[0];
    const float* emb    = (const float*)d_in[1];
    const float* W_f    = (const float*)d_in[2];
    const float* U_f    = (const float*)d_in[3];
    const float* b_f    = (const float*)d_in[4];
    const float* W_b    = (const float*)d_in[5];
    const float* U_b    = (const float*)d_in[6];
    const float* b_b    = (const float*)d_in[7];
    const float* W_d    = (const float*)d_in[8];
    const float* b_d    = (const float*)d_in[9];
    float* out = (float*)d_out;
    float* ws  = (float*)d_ws;

    const size_t HSLOT = (size_t)2 * BATCH * HID;        // 65536 floats
    const size_t U8SZ  = (size_t)2 * 64 * G4;            // 131072 dwords
    int chunk = 0;
    const int cand[4] = {512, 128, 64, 16};
    for (int i = 0; i < 4; ++i) {
        size_t need = ((size_t)2 * cand[i] * BATCH * G4 + 2 * HSLOT + U8SZ) * sizeof(float);
        if (ws_size >= need) { chunk = cand[i]; break; }
    }

    if (chunk == 0) {
        float* hbuf0 = ws;
        float* cbuf  = hbuf0 + HSLOT;
        float* hbuf1 = cbuf + HSLOT;
        hipMemsetAsync(hbuf0, 0, 2 * HSLOT * sizeof(float), stream);
        float* hin = hbuf0; float* hout = hbuf1;
        for (int s = 0; s < T_SEQ; ++s) {
            lstm_step_fb<<<dim3(16, 8, 2), 256, 0, stream>>>(
                tokens, emb, W_f, U_f, b_f, W_b, U_b, b_b, hin, hout, cbuf, s);
            float* tmp = hin; hin = hout; hout = tmp;
        }
        dense_softmax_v21<<<dim3(BATCH), 64, 0, stream>>>(hin, W_d, b_d, out);
        return;
    }

    float*    xw     = ws;                                  // [2][chunk][128][1024]
    float*    hstate = xw + (size_t)2 * chunk * BATCH * G4; // [2][128][256]
    float*    cstate = hstate + HSLOT;                      // [2][128][256]
    unsigned* u8     = (unsigned*)(cstate + HSLOT);         // [2][64][1024]

    hipMemsetAsync(hstate, 0, 2 * HSLOT * sizeof(float), stream);  // h0 + c0

    pack_u8_v21<<<dim3(512), 256, 0, stream>>>(U_f, U_b, u8);

    for (int c0 = 0; c0 < T_SEQ; c0 += chunk) {
        xw_gemm_mfma_v21<<<dim3(chunk * BATCH / 32, 4, 2), 256, 0, stream>>>(
            tokens, emb, W_f, b_f, W_b, b_b, xw, c0, chunk);
        lstm_scan_v21<<<dim3(128, 2), 1024, 0, stream>>>(
            xw, u8, hstate, cstate, chunk);
    }
    dense_softmax_v21<<<dim3(BATCH), 64, 0, stream>>>(hstate, W_d, b_d, out);
}